// Round 12
// baseline (315.017 us; speedup 1.0000x reference)
//
#include <hip/hip_runtime.h>
#include <math.h>

// NetNew_17162689315115: 8-layer EQL-style net, B=524288 rows.
// Reference is numpy float64; chaotic map (sin/cos at |z|~1e8-1e14) -> ENTIRE
// chain in fp64, bitwise-frozen since R3 (absmax 1245184 / thr 1646264).
// DO NOT reassociate: each z[j] = fma(W[j,k], h[k], acc) ascending k.
//
// Evidence log:
//  R4 407us (fp64 weights via d_ws). R5/R6 allocator hints: regress badly.
//  R7 block 64 vs 256: neutral. R8 j-blocking: exactly neutral (h "spills"
//  are AGPR moves in the unified file -> 2 waves/SIMD state cap, no scratch).
//  R9 I$ shrink (rolled j-loop + shared noinline transcendentals):
//  407 -> 222us. R10 merged transcendental call: neutral (branchy bodies
//  don't interleave). R11 inline exp/log: neutral.
// R12 theory: residual 44% idle = lgkmcnt serialization on s_load weight
// chunks (IN_DIM=71 -> 142 dwords/row >> 112-SGPR budget; chunk->wait->fma
// serial at 1.8 waves/SIMD). Fix: stage weights in LDS (block-cooperative
// fp32->fp64 widen, one barrier). Broadcast ds_read has a deep queue and
// overlaps the VALU; also kills the separate widen kernel (one dispatch).
// Block=256: 4 waves share one 33.5 KB LDS copy; 2 blocks/CU = 67 KB < 160.
// Bitwise-neutral: same fp64 values, same op order.

static constexpr double MAX_MLT   = 99999999.0;
static constexpr double MAX_DIV   = 9999.0;
static constexpr double MAX_EXP_C = 17.0;
static constexpr double MIN_DENOM = 0.0001;

static constexpr int IN0  = 8;   // vari_num + const_num
static constexpr int VDIM = 13;  // rows of each W
static constexpr int NOPS = 9;   // ops appended per layer
static constexpr int FDIM = 80;  // final h dim: 8 + 8*9

// layer weight element counts and fp64 offsets (concatenated)
// in_dims: 8,17,26,35,44,53,62,71 ; W_i is 13 x in_dim ; Wf is 1 x 80
static constexpr int WSZ[9]  = {104, 221, 338, 455, 572, 689, 806, 923, 80};
static constexpr int WOFF[9] = {0, 104, 325, 663, 1118, 1690, 2379, 3185, 4108};
static constexpr int WTOT    = 4188;  // doubles = 33504 B LDS

// ---- one shared body for the two PH-heavy (branchy) functions ----
struct D2 { double s, c; };
__device__ __attribute__((noinline))
D2 d_sincos2(double as, double ac) {
    D2 r;
    r.s = sin(as);
    r.c = cos(ac);
    return r;
}

// _clip_mag forward, float64: scale = |mx/v|, o = where(|v|>=mx, v*scale, v).
// NaN passes through (compare false), matching jnp.where.
__device__ __forceinline__ double clip_ref(double v, double mx) {
    double scale = fabs(mx / v);
    double vs    = v * scale;
    return (fabs(v) >= mx) ? vs : v;
}

template<int IN_DIM, int BASE>
__device__ __forceinline__ void layer_step(const double* __restrict__ W,
                                           double (&h)[FDIM]) {
    double z[VDIM];
    // Rolled j-loop (unroll 2): each z[j] is the same ascending-k fma chain
    // as the fully-unrolled form -> bitwise equal. k stays unrolled so every
    // h index is compile-time constant (register/AGPR-resident).
    #pragma unroll 2
    for (int j = 0; j < VDIM; ++j) {
        const double* Wr = W + j * IN_DIM;
        double acc = 0.0;
        #pragma unroll
        for (int k = 0; k < IN_DIM; ++k) {
            acc = fma(Wr[k], h[BASE + k], acc);  // frozen accum order
        }
        z[j] = acc;
    }
    constexpr int BO = BASE - NOPS;
    // op order: + - * / sin cos exp log square, consuming z cols in order
    h[BO + 0] = z[0] + z[1];
    h[BO + 1] = z[2] - z[3];
    h[BO + 2] = clip_ref(z[4] * z[5], MAX_MLT);
    {
        double b     = z[7];
        double denom = (b == 0.0) ? (b + MIN_DENOM) : b;
        h[BO + 3]    = clip_ref(z[6] / denom, MAX_DIV);
    }
    {
        D2 t = d_sincos2(z[8], z[9]);   // shared noinline: PH-heavy bodies
        h[BO + 4] = t.s;
        h[BO + 5] = t.c;
    }
    {
        double a    = z[10];
        double safe = (a >= MAX_EXP_C) ? (a * (MAX_EXP_C / a)) : a;
        h[BO + 6]   = exp(safe);        // inlined: branch-light
    }
    h[BO + 7] = log(fabs(z[11]));       // inlined: branch-light
    h[BO + 8] = clip_ref(z[12] * z[12], MAX_MLT);
}

__global__ void __launch_bounds__(256)
net_kernel(const float* __restrict__ x,
           const float* __restrict__ W1, const float* __restrict__ W2,
           const float* __restrict__ W3, const float* __restrict__ W4,
           const float* __restrict__ W5, const float* __restrict__ W6,
           const float* __restrict__ W7, const float* __restrict__ W8,
           const float* __restrict__ WfIn,
           float* __restrict__ out, int nrows) {
    __shared__ double Wl[WTOT];

    // block-cooperative widen fp32 -> fp64 LDS (exact; one-time ~1us)
    {
        const float* srcs[9] = {W1, W2, W3, W4, W5, W6, W7, W8, WfIn};
        #pragma unroll
        for (int s = 0; s < 9; ++s) {
            const float* src = srcs[s];
            double*      dst = Wl + WOFF[s];
            for (int i = threadIdx.x; i < WSZ[s]; i += 256) {
                dst[i] = (double)src[i];
            }
        }
        __syncthreads();
    }

    int row = blockIdx.x * blockDim.x + threadIdx.x;
    if (row >= nrows) return;

    double h[FDIM];

    // x occupies the TAIL of the final feature vector (each layer prepends).
    const float4* x4 = reinterpret_cast<const float4*>(x);
    float4 xa = x4[row * 2 + 0];
    float4 xb = x4[row * 2 + 1];
    h[72] = (double)xa.x; h[73] = (double)xa.y; h[74] = (double)xa.z; h[75] = (double)xa.w;
    h[76] = (double)xb.x; h[77] = (double)xb.y; h[78] = (double)xb.z; h[79] = (double)xb.w;

    layer_step<IN0 + 0 * NOPS, 72>(Wl + WOFF[0], h);  // in_dim  8, write at 63
    layer_step<IN0 + 1 * NOPS, 63>(Wl + WOFF[1], h);  // in_dim 17, write at 54
    layer_step<IN0 + 2 * NOPS, 54>(Wl + WOFF[2], h);  // in_dim 26, write at 45
    layer_step<IN0 + 3 * NOPS, 45>(Wl + WOFF[3], h);  // in_dim 35, write at 36
    layer_step<IN0 + 4 * NOPS, 36>(Wl + WOFF[4], h);  // in_dim 44, write at 27
    layer_step<IN0 + 5 * NOPS, 27>(Wl + WOFF[5], h);  // in_dim 53, write at 18
    layer_step<IN0 + 6 * NOPS, 18>(Wl + WOFF[6], h);  // in_dim 62, write at  9
    layer_step<IN0 + 7 * NOPS,  9>(Wl + WOFF[7], h);  // in_dim 71, write at  0

    // Final dot stays unrolled: h indices must remain static (any dynamic h
    // access would force the whole array to scratch).
    const double* Wf = Wl + WOFF[8];
    double acc = 0.0;
    #pragma unroll
    for (int k = 0; k < FDIM; ++k) {
        acc = fma(Wf[k], h[k], acc);
    }
    out[row] = (float)acc;
}

extern "C" void kernel_launch(void* const* d_in, const int* in_sizes, int n_in,
                              void* d_out, int out_size, void* d_ws, size_t ws_size,
                              hipStream_t stream) {
    const float* x = (const float*)d_in[0];
    float* out     = (float*)d_out;

    int nrows = in_sizes[0] / IN0;
    int block = 256;
    int grid  = (nrows + block - 1) / block;
    net_kernel<<<grid, block, 0, stream>>>(
        x,
        (const float*)d_in[1], (const float*)d_in[2], (const float*)d_in[3],
        (const float*)d_in[4], (const float*)d_in[5], (const float*)d_in[6],
        (const float*)d_in[7], (const float*)d_in[8], (const float*)d_in[9],
        out, nrows);
}

// Round 14
// 290.234 us; speedup vs baseline: 1.0854x; 1.0854x over previous
//
#include <hip/hip_runtime.h>
#include <math.h>

// NetNew_17162689315115: 8-layer EQL-style net, B=524288 rows.
// Reference is numpy float64; chaotic map (sin/cos at |z| up to ~1e8) -> the
// ENTIRE chain runs in fp64, bitwise-frozen since R3 (absmax 1245184 /
// thr 1646264). DO NOT reassociate: each z[j] = fma(W[j,k], h[k], acc)
// ascending k; final dot ascending k=0..79.
//
// Evidence log (what's proven, don't re-try):
//  R4 407us: fp64 weights pre-widened into d_ws; s_load path.
//  R5/R6 allocator hints (waves_per_eu, launch_bounds min): regress badly.
//  R7 block 64 vs 256: neutral. R8 j-blocking: exactly neutral (h "spills"
//    are AGPR moves in the unified file; ~220-reg state -> 2 waves/SIMD cap,
//    measured 1.8 across ALL configs; no scratch HBM traffic).
//  R9 I$ shrink (rolled j-loop + shared noinline transcendentals):
//    407 -> 222us, busy 265 -> 127us. I$ thrash was real.
//  R10 merged transcendental call / R11 inline exp+log: neutral.
//  R12 LDS-staged weights: REGRESS 214 -> 267us (ds_read+lgkmcnt in hot loop
//    is worse than s_load constant-cache path). Reverted.
// Structural model: issue floor ~120us; idle = fp64 dep-chain latency at the
// 2-wave/SIMD state cap (h[80] fp64 = 160 regs irreducibly live). LDS-backed
// h fails capacity arithmetic (40KB/wave -> 4 waves/CU < current 7.2).
//
// R14 = R13 with the compile fix (matvec epilogue call was missing the z
// arg). Epilogue fold: layer 8's nine op outputs are exactly terms k=0..8 of
// the final dot; fold them into acc in the same frozen order instead of
// keeping h[0..9) alive. Bitwise-identical chain.

static constexpr double MAX_MLT   = 99999999.0;
static constexpr double MAX_DIV   = 9999.0;
static constexpr double MAX_EXP_C = 17.0;
static constexpr double MIN_DENOM = 0.0001;

static constexpr int IN0  = 8;   // vari_num + const_num
static constexpr int VDIM = 13;  // rows of each W
static constexpr int NOPS = 9;   // ops appended per layer
static constexpr int FDIM = 80;  // final h dim: 8 + 8*9

// layer weight element counts and fp64 workspace offsets
// in_dims: 8,17,26,35,44,53,62,71 ; W_i is 13 x in_dim ; Wf is 1 x 80
static constexpr int WSZ[9]  = {104, 221, 338, 455, 572, 689, 806, 923, 80};
static constexpr int WOFF[9] = {0, 104, 325, 663, 1118, 1690, 2379, 3185, 4108};

// ---- prep: widen fp32 weights -> fp64 workspace (exact, bitwise-neutral) ----
__global__ void widen_kernel(const float* __restrict__ s0, const float* __restrict__ s1,
                             const float* __restrict__ s2, const float* __restrict__ s3,
                             const float* __restrict__ s4, const float* __restrict__ s5,
                             const float* __restrict__ s6, const float* __restrict__ s7,
                             const float* __restrict__ s8, double* __restrict__ dst) {
    int seg = blockIdx.y;
    int i   = blockIdx.x * blockDim.x + threadIdx.x;
    const float* src;
    switch (seg) {
        case 0: src = s0; break; case 1: src = s1; break; case 2: src = s2; break;
        case 3: src = s3; break; case 4: src = s4; break; case 5: src = s5; break;
        case 6: src = s6; break; case 7: src = s7; break; default: src = s8; break;
    }
    if (i < WSZ[seg]) dst[WOFF[seg] + i] = (double)src[i];
}

// ---- one shared body for the two PH-heavy (branchy) functions ----
struct D2 { double s, c; };
__device__ __attribute__((noinline))
D2 d_sincos2(double as, double ac) {
    D2 r;
    r.s = sin(as);
    r.c = cos(ac);
    return r;
}

// _clip_mag forward, float64: scale = |mx/v|, o = where(|v|>=mx, v*scale, v).
// NaN passes through (compare false), matching jnp.where.
__device__ __forceinline__ double clip_ref(double v, double mx) {
    double scale = fabs(mx / v);
    double vs    = v * scale;
    return (fabs(v) >= mx) ? vs : v;
}

// Matmul z = W(13 x IN_DIM) @ h[BASE..]; rolled j-loop (unroll 2): each z[j]
// is the same ascending-k fma chain as fully-unrolled -> bitwise equal.
// k stays unrolled so every h index is compile-time constant.
template<int IN_DIM, int BASE>
__device__ __forceinline__ void matvec(const double* __restrict__ W,
                                       const double (&h)[FDIM],
                                       double (&z)[VDIM]) {
    #pragma unroll 2
    for (int j = 0; j < VDIM; ++j) {
        const double* Wr = W + j * IN_DIM;
        double acc = 0.0;
        #pragma unroll
        for (int k = 0; k < IN_DIM; ++k) {
            acc = fma(Wr[k], h[BASE + k], acc);  // frozen accum order
        }
        z[j] = acc;
    }
}

// op order: + - * / sin cos exp log square, consuming z cols in order
template<int BASE>
__device__ __forceinline__ void apply_ops(const double (&z)[VDIM],
                                          double (&h)[FDIM]) {
    constexpr int BO = BASE - NOPS;
    h[BO + 0] = z[0] + z[1];
    h[BO + 1] = z[2] - z[3];
    h[BO + 2] = clip_ref(z[4] * z[5], MAX_MLT);
    {
        double b     = z[7];
        double denom = (b == 0.0) ? (b + MIN_DENOM) : b;
        h[BO + 3]    = clip_ref(z[6] / denom, MAX_DIV);
    }
    {
        D2 t = d_sincos2(z[8], z[9]);   // shared noinline: PH-heavy bodies
        h[BO + 4] = t.s;
        h[BO + 5] = t.c;
    }
    {
        double a    = z[10];
        double safe = (a >= MAX_EXP_C) ? (a * (MAX_EXP_C / a)) : a;
        h[BO + 6]   = exp(safe);        // inlined: branch-light
    }
    h[BO + 7] = log(fabs(z[11]));       // inlined: branch-light
    h[BO + 8] = clip_ref(z[12] * z[12], MAX_MLT);
}

template<int IN_DIM, int BASE>
__device__ __forceinline__ void layer_step(const double* __restrict__ W,
                                           double (&h)[FDIM]) {
    double z[VDIM];
    matvec<IN_DIM, BASE>(W, h, z);
    apply_ops<BASE>(z, h);
}

__global__ void __launch_bounds__(64)
net_kernel(const float* __restrict__ x, const double* __restrict__ Wd,
           float* __restrict__ out, int nrows) {
    int row = blockIdx.x * blockDim.x + threadIdx.x;
    if (row >= nrows) return;

    double h[FDIM];

    // x occupies the TAIL of the final feature vector (each layer prepends).
    const float4* x4 = reinterpret_cast<const float4*>(x);
    float4 xa = x4[row * 2 + 0];
    float4 xb = x4[row * 2 + 1];
    h[72] = (double)xa.x; h[73] = (double)xa.y; h[74] = (double)xa.z; h[75] = (double)xa.w;
    h[76] = (double)xb.x; h[77] = (double)xb.y; h[78] = (double)xb.z; h[79] = (double)xb.w;

    layer_step<IN0 + 0 * NOPS, 72>(Wd + WOFF[0], h);  // in_dim  8, write at 63
    layer_step<IN0 + 1 * NOPS, 63>(Wd + WOFF[1], h);  // in_dim 17, write at 54
    layer_step<IN0 + 2 * NOPS, 54>(Wd + WOFF[2], h);  // in_dim 26, write at 45
    layer_step<IN0 + 3 * NOPS, 45>(Wd + WOFF[3], h);  // in_dim 35, write at 36
    layer_step<IN0 + 4 * NOPS, 36>(Wd + WOFF[4], h);  // in_dim 44, write at 27
    layer_step<IN0 + 5 * NOPS, 27>(Wd + WOFF[5], h);  // in_dim 53, write at 18
    layer_step<IN0 + 6 * NOPS, 18>(Wd + WOFF[6], h);  // in_dim 62, write at  9

    // Layer 8: its 9 op outputs are exactly terms k=0..8 of the final dot.
    // Compute them, fold into acc in the SAME frozen order (k ascending),
    // then continue with k=9..79 from h. Bitwise-identical chain.
    const double* Wf = Wd + WOFF[8];
    double acc = 0.0;
    {
        double z[VDIM];
        matvec<IN0 + 7 * NOPS, 9>(Wd + WOFF[7], h, z);   // in_dim 71 -> z
        // apply ops into h[0..9) then immediately consume (compiler folds)
        apply_ops<9>(z, h);
        #pragma unroll
        for (int k = 0; k < NOPS; ++k) {
            acc = fma(Wf[k], h[k], acc);
        }
    }
    #pragma unroll
    for (int k = NOPS; k < FDIM; ++k) {
        acc = fma(Wf[k], h[k], acc);
    }
    out[row] = (float)acc;
}

extern "C" void kernel_launch(void* const* d_in, const int* in_sizes, int n_in,
                              void* d_out, int out_size, void* d_ws, size_t ws_size,
                              hipStream_t stream) {
    const float* x = (const float*)d_in[0];
    double* Wd     = (double*)d_ws;   // 4188 doubles = 33.5 KB
    float* out     = (float*)d_out;

    // widen weights (d_ws is re-poisoned before every call -> must rewrite)
    {
        dim3 grid((923 + 255) / 256, 9);
        widen_kernel<<<grid, 256, 0, stream>>>(
            (const float*)d_in[1], (const float*)d_in[2], (const float*)d_in[3],
            (const float*)d_in[4], (const float*)d_in[5], (const float*)d_in[6],
            (const float*)d_in[7], (const float*)d_in[8], (const float*)d_in[9],
            Wd);
    }

    int nrows = in_sizes[0] / IN0;
    int block = 64;
    int grid  = (nrows + block - 1) / block;
    net_kernel<<<grid, block, 0, stream>>>(x, Wd, out, nrows);
}

// Round 15
// 276.148 us; speedup vs baseline: 1.1408x; 1.0510x over previous
//
#include <hip/hip_runtime.h>
#include <math.h>

// NetNew_17162689315115: 8-layer EQL-style net, B=524288 rows.
// Reference is numpy float64; chaotic map (sin/cos at |z| up to ~1e8) -> the
// ENTIRE chain runs in fp64, bitwise-frozen since R3 (absmax 1245184 /
// thr 1646264). DO NOT reassociate: each z[j] = fma(W[j,k], h[k], acc)
// ascending k; final dot ascending k=0..79.
//
// FINAL CONFIGURATION (= R11, empirical optimum of 12 benched variants:
// kernel 213.5us, bench 275.8us). Evidence log:
//  R4 407us: fp64 weights pre-widened into d_ws; s_load path.
//  R5/R6 allocator hints (waves_per_eu, launch_bounds min): regress badly.
//  R7 block 64 vs 256: neutral. R8 j-blocking: exactly neutral (h "spills"
//    are AGPR moves in the unified file; ~220-reg state -> 2 waves/SIMD cap,
//    measured 1.8 across ALL configs; no scratch HBM traffic).
//  R9 I$ shrink (rolled j-loop + shared noinline transcendentals):
//    407 -> 222us, busy 265 -> 127us. I$ thrash was real.
//  R10 merged transcendental call: neutral (branchy bodies don't interleave).
//  R11 inline exp/log + shared sincos: 213.5us <- BEST.
//  R12 LDS-staged weights: regress 214 -> 267us (ds_read in hot loop loses
//    to s_load constant-cache path).
//  R14 epilogue fold of layer-8 into final dot: regress 214 -> 229us
//    (perturbs arch-VGPR/AGPR split; peak liveness unchanged).
// Structural ceiling: VALUBusy ~56% at a hard 1.8-waves/SIMD state cap
// (h[80] fp64 irreducibly live). Residual idle = fp64 dep-chain latency
// (branchy ocml sin/cos) that 2 waves cannot hide. All state-reduction
// paths fail: fp32/custom-sincos re-roll chaos vs 1.32x absmax margin;
// LDS-h and kernel-split fail capacity/traffic arithmetic.

static constexpr double MAX_MLT   = 99999999.0;
static constexpr double MAX_DIV   = 9999.0;
static constexpr double MAX_EXP_C = 17.0;
static constexpr double MIN_DENOM = 0.0001;

static constexpr int IN0  = 8;   // vari_num + const_num
static constexpr int VDIM = 13;  // rows of each W
static constexpr int NOPS = 9;   // ops appended per layer
static constexpr int FDIM = 80;  // final h dim: 8 + 8*9

// layer weight element counts and fp64 workspace offsets
// in_dims: 8,17,26,35,44,53,62,71 ; W_i is 13 x in_dim ; Wf is 1 x 80
static constexpr int WSZ[9]  = {104, 221, 338, 455, 572, 689, 806, 923, 80};
static constexpr int WOFF[9] = {0, 104, 325, 663, 1118, 1690, 2379, 3185, 4108};

// ---- prep: widen fp32 weights -> fp64 workspace (exact, bitwise-neutral) ----
__global__ void widen_kernel(const float* __restrict__ s0, const float* __restrict__ s1,
                             const float* __restrict__ s2, const float* __restrict__ s3,
                             const float* __restrict__ s4, const float* __restrict__ s5,
                             const float* __restrict__ s6, const float* __restrict__ s7,
                             const float* __restrict__ s8, double* __restrict__ dst) {
    int seg = blockIdx.y;
    int i   = blockIdx.x * blockDim.x + threadIdx.x;
    const float* src;
    switch (seg) {
        case 0: src = s0; break; case 1: src = s1; break; case 2: src = s2; break;
        case 3: src = s3; break; case 4: src = s4; break; case 5: src = s5; break;
        case 6: src = s6; break; case 7: src = s7; break; default: src = s8; break;
    }
    if (i < WSZ[seg]) dst[WOFF[seg] + i] = (double)src[i];
}

// ---- one shared body for the two PH-heavy (branchy) functions ----
struct D2 { double s, c; };
__device__ __attribute__((noinline))
D2 d_sincos2(double as, double ac) {
    D2 r;
    r.s = sin(as);
    r.c = cos(ac);
    return r;
}

// _clip_mag forward, float64: scale = |mx/v|, o = where(|v|>=mx, v*scale, v).
// NaN passes through (compare false), matching jnp.where.
__device__ __forceinline__ double clip_ref(double v, double mx) {
    double scale = fabs(mx / v);
    double vs    = v * scale;
    return (fabs(v) >= mx) ? vs : v;
}

template<int IN_DIM, int BASE>
__device__ __forceinline__ void layer_step(const double* __restrict__ W,
                                           double (&h)[FDIM]) {
    double z[VDIM];
    // Rolled j-loop (unroll 2): each z[j] is the same ascending-k fma chain
    // as the fully-unrolled form -> bitwise equal. k stays unrolled so every
    // h index is compile-time constant (register/AGPR-resident).
    #pragma unroll 2
    for (int j = 0; j < VDIM; ++j) {
        const double* Wr = W + j * IN_DIM;
        double acc = 0.0;
        #pragma unroll
        for (int k = 0; k < IN_DIM; ++k) {
            acc = fma(Wr[k], h[BASE + k], acc);  // frozen accum order
        }
        z[j] = acc;
    }
    constexpr int BO = BASE - NOPS;
    // op order: + - * / sin cos exp log square, consuming z cols in order
    h[BO + 0] = z[0] + z[1];
    h[BO + 1] = z[2] - z[3];
    h[BO + 2] = clip_ref(z[4] * z[5], MAX_MLT);
    {
        double b     = z[7];
        double denom = (b == 0.0) ? (b + MIN_DENOM) : b;
        h[BO + 3]    = clip_ref(z[6] / denom, MAX_DIV);
    }
    {
        D2 t = d_sincos2(z[8], z[9]);   // shared noinline: PH-heavy bodies
        h[BO + 4] = t.s;
        h[BO + 5] = t.c;
    }
    {
        double a    = z[10];
        double safe = (a >= MAX_EXP_C) ? (a * (MAX_EXP_C / a)) : a;
        h[BO + 6]   = exp(safe);        // inlined: branch-light, schedules in
    }
    h[BO + 7] = log(fabs(z[11]));       // inlined: branch-light
    h[BO + 8] = clip_ref(z[12] * z[12], MAX_MLT);
}

__global__ void __launch_bounds__(64)
net_kernel(const float* __restrict__ x, const double* __restrict__ Wd,
           float* __restrict__ out, int nrows) {
    int row = blockIdx.x * blockDim.x + threadIdx.x;
    if (row >= nrows) return;

    double h[FDIM];

    // x occupies the TAIL of the final feature vector (each layer prepends).
    const float4* x4 = reinterpret_cast<const float4*>(x);
    float4 xa = x4[row * 2 + 0];
    float4 xb = x4[row * 2 + 1];
    h[72] = (double)xa.x; h[73] = (double)xa.y; h[74] = (double)xa.z; h[75] = (double)xa.w;
    h[76] = (double)xb.x; h[77] = (double)xb.y; h[78] = (double)xb.z; h[79] = (double)xb.w;

    layer_step<IN0 + 0 * NOPS, 72>(Wd + WOFF[0], h);  // in_dim  8, write at 63
    layer_step<IN0 + 1 * NOPS, 63>(Wd + WOFF[1], h);  // in_dim 17, write at 54
    layer_step<IN0 + 2 * NOPS, 54>(Wd + WOFF[2], h);  // in_dim 26, write at 45
    layer_step<IN0 + 3 * NOPS, 45>(Wd + WOFF[3], h);  // in_dim 35, write at 36
    layer_step<IN0 + 4 * NOPS, 36>(Wd + WOFF[4], h);  // in_dim 44, write at 27
    layer_step<IN0 + 5 * NOPS, 27>(Wd + WOFF[5], h);  // in_dim 53, write at 18
    layer_step<IN0 + 6 * NOPS, 18>(Wd + WOFF[6], h);  // in_dim 62, write at  9
    layer_step<IN0 + 7 * NOPS,  9>(Wd + WOFF[7], h);  // in_dim 71, write at  0

    // Final dot stays unrolled: h indices must remain static (any dynamic h
    // access would force the whole array to scratch).
    const double* Wf = Wd + WOFF[8];
    double acc = 0.0;
    #pragma unroll
    for (int k = 0; k < FDIM; ++k) {
        acc = fma(Wf[k], h[k], acc);
    }
    out[row] = (float)acc;
}

extern "C" void kernel_launch(void* const* d_in, const int* in_sizes, int n_in,
                              void* d_out, int out_size, void* d_ws, size_t ws_size,
                              hipStream_t stream) {
    const float* x = (const float*)d_in[0];
    double* Wd     = (double*)d_ws;   // 4188 doubles = 33.5 KB
    float* out     = (float*)d_out;

    // widen weights (d_ws is re-poisoned before every call -> must rewrite)
    {
        dim3 grid((923 + 255) / 256, 9);
        widen_kernel<<<grid, 256, 0, stream>>>(
            (const float*)d_in[1], (const float*)d_in[2], (const float*)d_in[3],
            (const float*)d_in[4], (const float*)d_in[5], (const float*)d_in[6],
            (const float*)d_in[7], (const float*)d_in[8], (const float*)d_in[9],
            Wd);
    }

    int nrows = in_sizes[0] / IN0;
    int block = 64;
    int grid  = (nrows + block - 1) / block;
    net_kernel<<<grid, block, 0, stream>>>(x, Wd, out, nrows);
}